// Round 2
// baseline (41.534 us; speedup 1.0000x reference)
//
#include <hip/hip_runtime.h>

// ---------------------------------------------------------------------------
// StructuralConstraints: RNA base-pair mask + stacking-energy update.
// ref: mask[b,i,j] = valid(si,sj) * (|i-j|>=3 & i<len & j<len)
//      updated[b,i,j] = bp[b,i,j] + add[b,i,j] + add[b,j,i]
//      add[b,i,j] = S(i,j) + (i>=1 && j<=L-2 ? S(i-1,j+1) : 0)
//      S(r,c) = region(r,c) ? E[seq[r],seq[c],seq[(r+1)%L],seq[(c-1)%L]] : 0
//      region(r,c) = (c-r>=4) & (r<len-1) & (c<len)
// Memory-bound: 64 MiB read + 128 MiB write -> ~31us at 6.4 TB/s mixed.
// R1: ROWS=4 rows/block (amortize staging+syncs 4x), 4-deep load prefetch
//     per thread for MLP, nontemporal loads/stores (streaming data).
// ---------------------------------------------------------------------------

typedef float f4 __attribute__((ext_vector_type(4)));
typedef int   i4 __attribute__((ext_vector_type(4)));

struct ETab { float v[256]; };

constexpr bool vp(int a, int b) { return (a - b == 1) || (b - a == 1); }

constexpr ETab make_E() {
    ETab t{};
    for (int a = 0; a < 4; ++a)
    for (int b = 0; b < 4; ++b)
    for (int c = 0; c < 4; ++c)
    for (int d = 0; d < 4; ++d) {
        float val = 0.0f;
        if (vp(a, b) && vp(c, d)) {
            val = 0.5f;  // default stacking energy
            // STACK overrides (A=0,U=1,G=2,C=3)
            if      (a==0 && b==1 && c==0 && d==1) val = 0.9f;
            else if (a==0 && b==1 && c==2 && d==3) val = 1.1f;
            else if (a==0 && b==1 && c==2 && d==1) val = 0.8f;
            else if (a==2 && b==3 && c==0 && d==1) val = 1.1f;
            else if (a==2 && b==3 && c==2 && d==3) val = 1.3f;
            else if (a==2 && b==3 && c==2 && d==1) val = 1.0f;
            else if (a==2 && b==1 && c==0 && d==1) val = 0.8f;
            else if (a==2 && b==1 && c==2 && d==3) val = 1.0f;
            else if (a==2 && b==1 && c==2 && d==1) val = 0.7f;
        }
        t.v[((a * 4 + b) * 4 + c) * 4 + d] = val;
    }
    return t;
}

__device__ __constant__ ETab cE = make_E();

#define ROWS 4

// One block per (b, 4 rows); 256 threads; each thread does 4 consecutive j
// per row, with all ROWS bp loads issued before any compute (MLP).
__global__ __launch_bounds__(256) void sc_kernel(
    const float* __restrict__ bp,
    const int*   __restrict__ seq,
    const int*   __restrict__ lens,
    float* __restrict__ mask_out,
    float* __restrict__ upd_out,
    int L)
{
    extern __shared__ char smem_raw[];
    int*   sseq = (int*)smem_raw;                          // L ints
    float (*T)[64] = (float(*)[64])(smem_raw + (size_t)L * 4);  // ROWS x 64

    const int i0  = blockIdx.x * ROWS;
    const int b   = blockIdx.y;
    const int tid = threadIdx.x;
    const int len = lens[b];
    const int* srow = seq + (size_t)b * L;

    // stage sequence row into LDS (int4, coalesced; seq is L2-resident)
    for (int k = tid; k < (L >> 2); k += blockDim.x)
        ((i4*)sseq)[k] = ((const i4*)srow)[k];

    // per-row E sub-tables: ROWS rows x 4 tables x 16 entries, one per thread
    for (int t0 = tid; t0 < ROWS * 64; t0 += blockDim.x) {
        const int r = t0 >> 6;
        const int t = (t0 >> 4) & 3;
        const int e = t0 & 15;
        const int p = e >> 2, q = e & 3;
        const int i = i0 + r;
        const int si   = srow[i];
        const int sim1 = srow[(i == 0)     ? (L - 1) : (i - 1)];
        const int sip1 = srow[(i == L - 1) ? 0       : (i + 1)];
        float v;
        if      (t == 0) v = cE.v[((si   * 4 + p) * 4 + sip1) * 4 + q];  // S(i,j)
        else if (t == 1) v = cE.v[((sim1 * 4 + p) * 4 + si  ) * 4 + q];  // S(i-1,j+1)
        else if (t == 2) v = cE.v[((p * 4 + si) * 4 + q) * 4 + sim1];    // S(j,i)
        else             v = cE.v[((p * 4 + sip1) * 4 + q) * 4 + si];    // S(j-1,i+1)
        T[r][t0 & 63] = v;
    }
    __syncthreads();

    const size_t base = ((size_t)b * L + i0) * L;

    for (int j0 = tid << 2; j0 < L; j0 += (int)blockDim.x << 2) {
        const i4 s4 = *(const i4*)&sseq[j0];
        const int sm = sseq[(j0 == 0)     ? (L - 1) : (j0 - 1)];
        const int sp = sseq[(j0 + 4 == L) ? 0       : (j0 + 4)];
        const int sj_[4]  = { s4[0], s4[1], s4[2], s4[3] };
        const int sjm_[4] = { sm,    s4[0], s4[1], s4[2] };
        const int sjp_[4] = { s4[1], s4[2], s4[3], sp    };

        // prefetch all ROWS bp quads -> 4 loads in flight per thread
        f4 bpv[ROWS];
        #pragma unroll
        for (int r = 0; r < ROWS; ++r)
            bpv[r] = __builtin_nontemporal_load(
                         (const f4*)(bp + base + (size_t)r * L + j0));

        #pragma unroll
        for (int r = 0; r < ROWS; ++r) {
            const int i  = i0 + r;
            const int si = sseq[i];  // LDS broadcast (wave-uniform)
            const bool i_lt_len   = i < len;
            const bool i_lt_lenm1 = i < len - 1;
            const bool ip1_lt_len = (i + 1) < len;
            const bool i_ge_1     = i >= 1;
            const float* T1 = T[r];
            const float* T2 = T[r] + 16;
            const float* T3 = T[r] + 32;
            const float* T4 = T[r] + 48;

            f4 mv, uv;
            #pragma unroll
            for (int k = 0; k < 4; ++k) {
                const int j = j0 + k;
                const int d = j - i;
                const bool j_lt_len = j < len;

                const bool pair_ok = ((si - sj_[k]) == 1) || ((sj_[k] - si) == 1);
                mv[k] = (pair_ok && (d >= 3 || d <= -3) && i_lt_len && j_lt_len)
                            ? 1.0f : 0.0f;

                float s = bpv[r][k];
                if (d >= 2) {           // forward: S(i,j) + S(i-1,j+1)
                    const float s1 = (d >= 4 && i_lt_lenm1 && j_lt_len)
                                       ? T1[sj_[k] * 4 + sjm_[k]] : 0.0f;
                    const float s2 = (i_ge_1 && i_lt_len && (j + 1) < len)
                                       ? T2[sjp_[k] * 4 + sj_[k]] : 0.0f;
                    s += s1 + s2;
                } else if (d <= -2) {   // transposed: S(j,i) + S(j-1,i+1)
                    const float s3 = (d <= -4 && (j < len - 1) && i_lt_len)
                                       ? T3[sj_[k] * 4 + sjp_[k]] : 0.0f;
                    const float s4v = (j >= 1 && j_lt_len && ip1_lt_len)
                                       ? T4[sjm_[k] * 4 + sj_[k]] : 0.0f;
                    s += s3 + s4v;
                }
                uv[k] = s;
            }

            __builtin_nontemporal_store(mv, (f4*)(mask_out + base + (size_t)r * L + j0));
            __builtin_nontemporal_store(uv, (f4*)(upd_out  + base + (size_t)r * L + j0));
        }
    }
}

extern "C" void kernel_launch(void* const* d_in, const int* in_sizes, int n_in,
                              void* d_out, int out_size, void* d_ws, size_t ws_size,
                              hipStream_t stream) {
    const float* bp   = (const float*)d_in[0];
    const int*   seq  = (const int*)d_in[1];
    const int*   lens = (const int*)d_in[2];

    const int B = in_sizes[2];
    const int L = in_sizes[1] / B;

    float* mask_out = (float*)d_out;
    float* upd_out  = (float*)d_out + (size_t)B * L * L;

    dim3 grid(L / ROWS, B);
    const size_t shmem = (size_t)L * sizeof(int) + ROWS * 64 * sizeof(float);
    sc_kernel<<<grid, 256, shmem, stream>>>(bp, seq, lens, mask_out, upd_out, L);
}

// Round 3
// 36.032 us; speedup vs baseline: 1.1527x; 1.1527x over previous
//
#include <hip/hip_runtime.h>

// ---------------------------------------------------------------------------
// StructuralConstraints: RNA base-pair mask + stacking-energy update.
// ref: mask[b,i,j] = valid(si,sj) * (|i-j|>=3 & i<len & j<len)
//      updated[b,i,j] = bp[b,i,j] + add[b,i,j] + add[b,j,i]
//      add[b,i,j] = S(i,j) + (i>=1 && j<=L-2 ? S(i-1,j+1) : 0)
//      S(r,c) = region(r,c) ? E[seq[r],seq[c],seq[(r+1)%L],seq[(c-1)%L]] : 0
// Memory-bound: 64 MiB read + 128 MiB write -> ~30us at 6.4 TB/s mixed.
// R2: back to R0 shape (1 row/block, known 35.3us). Remove ALL LDS + both
//     __syncthreads: E sub-tables packed as 64-bit nibble constants (E*10
//     fits 4 bits), fetched as ONE uniform scalar load each; seq read
//     directly from global (L1/L2-hot, ~1024 blocks share each 4KiB row).
//     Lookup = (T >> 4*idx) & 15, * 0.1f  (~4 VALU, no memory).
// ---------------------------------------------------------------------------

typedef float f4 __attribute__((ext_vector_type(4)));
typedef int   i4 __attribute__((ext_vector_type(4)));

constexpr bool vp(int a, int b) { return (a - b == 1) || (b - a == 1); }

// E * 10 as an integer (values {0,5,7,8,9,10,11,13} all fit in a nibble)
constexpr int ei(int a, int b, int c, int d) {
    if (!vp(a, b) || !vp(c, d)) return 0;
    if (a == 0 && b == 1) {               // (A,U) outer
        if (c == 0 && d == 1) return 9;   // (A,U,A,U) 0.9
        if (c == 2 && d == 3) return 11;  // (A,U,G,C) 1.1
        if (c == 2 && d == 1) return 8;   // (A,U,G,U) 0.8
    }
    if (a == 2 && b == 3) {               // (G,C) outer
        if (c == 0 && d == 1) return 11;  // 1.1
        if (c == 2 && d == 3) return 13;  // 1.3
        if (c == 2 && d == 1) return 10;  // 1.0
    }
    if (a == 2 && b == 1) {               // (G,U) outer
        if (c == 0 && d == 1) return 8;   // 0.8
        if (c == 2 && d == 3) return 10;  // 1.0
        if (c == 2 && d == 1) return 7;   // 0.7
    }
    return 5;                             // default 0.5
}

struct ETabs {
    unsigned long long fwd[16];  // fwd[a*4+c]: nibble (b*4+d) = ei(a,b,c,d)
    unsigned long long tr[16];   // tr [b*4+d]: nibble (a*4+c) = ei(a,b,c,d)
};

constexpr ETabs make_tabs() {
    ETabs t{};
    for (int a = 0; a < 4; ++a)
    for (int c = 0; c < 4; ++c) {
        unsigned long long v = 0;
        for (int b = 0; b < 4; ++b)
        for (int d = 0; d < 4; ++d)
            v |= (unsigned long long)ei(a, b, c, d) << ((b * 4 + d) * 4);
        t.fwd[a * 4 + c] = v;
    }
    for (int b = 0; b < 4; ++b)
    for (int d = 0; d < 4; ++d) {
        unsigned long long v = 0;
        for (int a = 0; a < 4; ++a)
        for (int c = 0; c < 4; ++c)
            v |= (unsigned long long)ei(a, b, c, d) << ((a * 4 + c) * 4);
        t.tr[b * 4 + d] = v;
    }
    return t;
}

__device__ __constant__ ETabs cT = make_tabs();

__device__ __forceinline__ float nibf(unsigned long long t, int idx) {
    return (float)((unsigned)(t >> (idx << 2)) & 15u) * 0.1f;
}

// One block per (b, i) row; 256 threads; each thread does 4 consecutive j.
// No LDS, no barriers.
__global__ __launch_bounds__(256) void sc_kernel(
    const float* __restrict__ bp,
    const int*   __restrict__ seq,
    const int*   __restrict__ lens,
    float* __restrict__ mask_out,
    float* __restrict__ upd_out,
    int L)
{
    const int i   = blockIdx.x;
    const int b   = blockIdx.y;
    const int tid = threadIdx.x;
    const int len = lens[b];
    const int* srow = seq + (size_t)b * L;

    // wave-uniform row codes + packed tables (scalar loads, no LDS)
    const int si   = srow[i];
    const int sim1 = srow[(i == 0)     ? (L - 1) : (i - 1)];
    const int sip1 = srow[(i == L - 1) ? 0       : (i + 1)];

    const unsigned long long T1 = cT.fwd[si   * 4 + sip1];  // S(i,j):     idx sj*4+sjm
    const unsigned long long T2 = cT.fwd[sim1 * 4 + si  ];  // S(i-1,j+1): idx sjp*4+sj
    const unsigned long long T3 = cT.tr [si   * 4 + sim1];  // S(j,i):     idx sj*4+sjp
    const unsigned long long T4 = cT.tr [sip1 * 4 + si  ];  // S(j-1,i+1): idx sjm*4+sj

    const size_t rowoff     = ((size_t)b * L + i) * L;
    const bool   i_lt_len   = i < len;
    const bool   i_lt_lenm1 = i < len - 1;
    const bool   ip1_lt_len = (i + 1) < len;
    const bool   i_ge_1     = i >= 1;

    for (int j0 = tid << 2; j0 < L; j0 += (int)blockDim.x << 2) {
        // j-neighborhood codes straight from global (L1/L2-hot 4KiB row)
        const i4 s4 = *(const i4*)&srow[j0];
        const int sm = srow[(j0 == 0)     ? (L - 1) : (j0 - 1)];
        const int sp = srow[(j0 + 4 == L) ? 0       : (j0 + 4)];
        const int sj_[4]  = { s4[0], s4[1], s4[2], s4[3] };
        const int sjm_[4] = { sm,    s4[0], s4[1], s4[2] };
        const int sjp_[4] = { s4[1], s4[2], s4[3], sp    };

        const f4 bp4 = *(const f4*)&bp[rowoff + j0];

        f4 mv, uv;
        #pragma unroll
        for (int k = 0; k < 4; ++k) {
            const int j = j0 + k;
            const int d = j - i;
            const bool j_lt_len = j < len;

            const bool pair_ok = ((si - sj_[k]) == 1) || ((sj_[k] - si) == 1);
            mv[k] = (pair_ok && (d >= 3 || d <= -3) && i_lt_len && j_lt_len)
                        ? 1.0f : 0.0f;

            float s = bp4[k];
            if (d >= 2) {           // forward: S(i,j) + S(i-1,j+1)
                const float s1 = (d >= 4 && i_lt_lenm1 && j_lt_len)
                                   ? nibf(T1, sj_[k] * 4 + sjm_[k]) : 0.0f;
                const float s2 = (i_ge_1 && i_lt_len && (j + 1) < len)
                                   ? nibf(T2, sjp_[k] * 4 + sj_[k]) : 0.0f;
                s += s1 + s2;
            } else if (d <= -2) {   // transposed: S(j,i) + S(j-1,i+1)
                const float s3 = (d <= -4 && (j < len - 1) && i_lt_len)
                                   ? nibf(T3, sj_[k] * 4 + sjp_[k]) : 0.0f;
                const float s4v = (j >= 1 && j_lt_len && ip1_lt_len)
                                   ? nibf(T4, sjm_[k] * 4 + sj_[k]) : 0.0f;
                s += s3 + s4v;
            }
            uv[k] = s;
        }

        *(f4*)&mask_out[rowoff + j0] = mv;
        *(f4*)&upd_out [rowoff + j0] = uv;
    }
}

extern "C" void kernel_launch(void* const* d_in, const int* in_sizes, int n_in,
                              void* d_out, int out_size, void* d_ws, size_t ws_size,
                              hipStream_t stream) {
    const float* bp   = (const float*)d_in[0];
    const int*   seq  = (const int*)d_in[1];
    const int*   lens = (const int*)d_in[2];

    const int B = in_sizes[2];
    const int L = in_sizes[1] / B;

    float* mask_out = (float*)d_out;
    float* upd_out  = (float*)d_out + (size_t)B * L * L;

    dim3 grid(L, B);
    sc_kernel<<<grid, 256, 0, stream>>>(bp, seq, lens, mask_out, upd_out, L);
}

// Round 4
// 34.506 us; speedup vs baseline: 1.2037x; 1.0442x over previous
//
#include <hip/hip_runtime.h>

// ---------------------------------------------------------------------------
// StructuralConstraints: RNA base-pair mask + stacking-energy update.
// ref: mask[b,i,j] = valid(si,sj) * (|i-j|>=3 & i<len & j<len)
//      updated[b,i,j] = bp[b,i,j] + add[b,i,j] + add[b,j,i]
//      add[b,i,j] = S(i,j) + (i>=1 && j<=L-2 ? S(i-1,j+1) : 0)
//      S(r,c) = region(r,c) ? E[seq[r],seq[c],seq[(r+1)%L],seq[(c-1)%L]] : 0
// Memory-bound: 64 MiB read + 128 MiB write.
// R2: no-LDS, no-barrier; E sub-tables as 64-bit nibble constants in SGPRs.
// R3: nontemporal STORES only (outputs never re-read -> don't allocate in
//     L2/L3). Goal: keep bp (64 MiB) resident in the 256 MiB Infinity Cache
//     across graph replays so HBM sees only the write stream.
// ---------------------------------------------------------------------------

typedef float f4 __attribute__((ext_vector_type(4)));
typedef int   i4 __attribute__((ext_vector_type(4)));

constexpr bool vp(int a, int b) { return (a - b == 1) || (b - a == 1); }

// E * 10 as an integer (values {0,5,7,8,9,10,11,13} all fit in a nibble)
constexpr int ei(int a, int b, int c, int d) {
    if (!vp(a, b) || !vp(c, d)) return 0;
    if (a == 0 && b == 1) {               // (A,U) outer
        if (c == 0 && d == 1) return 9;   // 0.9
        if (c == 2 && d == 3) return 11;  // 1.1
        if (c == 2 && d == 1) return 8;   // 0.8
    }
    if (a == 2 && b == 3) {               // (G,C) outer
        if (c == 0 && d == 1) return 11;  // 1.1
        if (c == 2 && d == 3) return 13;  // 1.3
        if (c == 2 && d == 1) return 10;  // 1.0
    }
    if (a == 2 && b == 1) {               // (G,U) outer
        if (c == 0 && d == 1) return 8;   // 0.8
        if (c == 2 && d == 3) return 10;  // 1.0
        if (c == 2 && d == 1) return 7;   // 0.7
    }
    return 5;                             // default 0.5
}

struct ETabs {
    unsigned long long fwd[16];  // fwd[a*4+c]: nibble (b*4+d) = ei(a,b,c,d)
    unsigned long long tr[16];   // tr [b*4+d]: nibble (a*4+c) = ei(a,b,c,d)
};

constexpr ETabs make_tabs() {
    ETabs t{};
    for (int a = 0; a < 4; ++a)
    for (int c = 0; c < 4; ++c) {
        unsigned long long v = 0;
        for (int b = 0; b < 4; ++b)
        for (int d = 0; d < 4; ++d)
            v |= (unsigned long long)ei(a, b, c, d) << ((b * 4 + d) * 4);
        t.fwd[a * 4 + c] = v;
    }
    for (int b = 0; b < 4; ++b)
    for (int d = 0; d < 4; ++d) {
        unsigned long long v = 0;
        for (int a = 0; a < 4; ++a)
        for (int c = 0; c < 4; ++c)
            v |= (unsigned long long)ei(a, b, c, d) << ((a * 4 + c) * 4);
        t.tr[b * 4 + d] = v;
    }
    return t;
}

__device__ __constant__ ETabs cT = make_tabs();

__device__ __forceinline__ float nibf(unsigned long long t, int idx) {
    return (float)((unsigned)(t >> (idx << 2)) & 15u) * 0.1f;
}

// One block per (b, i) row; 256 threads; each thread does 4 consecutive j.
// No LDS, no barriers.
__global__ __launch_bounds__(256) void sc_kernel(
    const float* __restrict__ bp,
    const int*   __restrict__ seq,
    const int*   __restrict__ lens,
    float* __restrict__ mask_out,
    float* __restrict__ upd_out,
    int L)
{
    const int i   = blockIdx.x;
    const int b   = blockIdx.y;
    const int tid = threadIdx.x;
    const int len = lens[b];
    const int* srow = seq + (size_t)b * L;

    // wave-uniform row codes + packed tables (scalar loads, no LDS)
    const int si   = srow[i];
    const int sim1 = srow[(i == 0)     ? (L - 1) : (i - 1)];
    const int sip1 = srow[(i == L - 1) ? 0       : (i + 1)];

    const unsigned long long T1 = cT.fwd[si   * 4 + sip1];  // S(i,j):     idx sj*4+sjm
    const unsigned long long T2 = cT.fwd[sim1 * 4 + si  ];  // S(i-1,j+1): idx sjp*4+sj
    const unsigned long long T3 = cT.tr [si   * 4 + sim1];  // S(j,i):     idx sj*4+sjp
    const unsigned long long T4 = cT.tr [sip1 * 4 + si  ];  // S(j-1,i+1): idx sjm*4+sj

    const size_t rowoff     = ((size_t)b * L + i) * L;
    const bool   i_lt_len   = i < len;
    const bool   i_lt_lenm1 = i < len - 1;
    const bool   ip1_lt_len = (i + 1) < len;
    const bool   i_ge_1     = i >= 1;

    for (int j0 = tid << 2; j0 < L; j0 += (int)blockDim.x << 2) {
        // j-neighborhood codes straight from global (L1/L2-hot 4KiB row)
        const i4 s4 = *(const i4*)&srow[j0];
        const int sm = srow[(j0 == 0)     ? (L - 1) : (j0 - 1)];
        const int sp = srow[(j0 + 4 == L) ? 0       : (j0 + 4)];
        const int sj_[4]  = { s4[0], s4[1], s4[2], s4[3] };
        const int sjm_[4] = { sm,    s4[0], s4[1], s4[2] };
        const int sjp_[4] = { s4[1], s4[2], s4[3], sp    };

        const f4 bp4 = *(const f4*)&bp[rowoff + j0];

        f4 mv, uv;
        #pragma unroll
        for (int k = 0; k < 4; ++k) {
            const int j = j0 + k;
            const int d = j - i;
            const bool j_lt_len = j < len;

            const bool pair_ok = ((si - sj_[k]) == 1) || ((sj_[k] - si) == 1);
            mv[k] = (pair_ok && (d >= 3 || d <= -3) && i_lt_len && j_lt_len)
                        ? 1.0f : 0.0f;

            float s = bp4[k];
            if (d >= 2) {           // forward: S(i,j) + S(i-1,j+1)
                const float s1 = (d >= 4 && i_lt_lenm1 && j_lt_len)
                                   ? nibf(T1, sj_[k] * 4 + sjm_[k]) : 0.0f;
                const float s2 = (i_ge_1 && i_lt_len && (j + 1) < len)
                                   ? nibf(T2, sjp_[k] * 4 + sj_[k]) : 0.0f;
                s += s1 + s2;
            } else if (d <= -2) {   // transposed: S(j,i) + S(j-1,i+1)
                const float s3 = (d <= -4 && (j < len - 1) && i_lt_len)
                                   ? nibf(T3, sj_[k] * 4 + sjp_[k]) : 0.0f;
                const float s4v = (j >= 1 && j_lt_len && ip1_lt_len)
                                   ? nibf(T4, sjm_[k] * 4 + sj_[k]) : 0.0f;
                s += s3 + s4v;
            }
            uv[k] = s;
        }

        __builtin_nontemporal_store(mv, (f4*)&mask_out[rowoff + j0]);
        __builtin_nontemporal_store(uv, (f4*)&upd_out [rowoff + j0]);
    }
}

extern "C" void kernel_launch(void* const* d_in, const int* in_sizes, int n_in,
                              void* d_out, int out_size, void* d_ws, size_t ws_size,
                              hipStream_t stream) {
    const float* bp   = (const float*)d_in[0];
    const int*   seq  = (const int*)d_in[1];
    const int*   lens = (const int*)d_in[2];

    const int B = in_sizes[2];
    const int L = in_sizes[1] / B;

    float* mask_out = (float*)d_out;
    float* upd_out  = (float*)d_out + (size_t)B * L * L;

    dim3 grid(L, B);
    sc_kernel<<<grid, 256, 0, stream>>>(bp, seq, lens, mask_out, upd_out, L);
}